// Round 2
// baseline (599.395 us; speedup 1.0000x reference)
//
#include <hip/hip_runtime.h>
#include <hip/hip_bf16.h>

#define LRELU_ALPHA 0.2f

typedef __bf16 bf16x8 __attribute__((ext_vector_type(8)));
typedef __bf16 bf16x4 __attribute__((ext_vector_type(4)));
typedef float f32x4 __attribute__((ext_vector_type(4)));

__device__ __forceinline__ float waveReduceSum(float v) {
#pragma unroll
    for (int off = 32; off > 0; off >>= 1)
        v += __shfl_xor(v, off, 64);
    return v;
}

// Fused: ABf = bf16(a); vall[k] = sum_o a[o*320+k]*a2[o]; cnt[src]++ per edge.
__global__ void k_prep_count(const float* __restrict__ a, const float* __restrict__ a2,
                             float* __restrict__ vall, __hip_bfloat16* __restrict__ ABf,
                             const int* __restrict__ e1, int E1,
                             const int* __restrict__ e2, int E2, int* __restrict__ cnt) {
    int idx = blockIdx.x * 256 + threadIdx.x;
    if (idx < 128 * 320) ABf[idx] = __float2bfloat16(a[idx]);
    if (idx < 320) {
        float s = 0.f;
#pragma unroll 8
        for (int o = 0; o < 128; ++o) s += a[o * 320 + idx] * a2[o];
        vall[idx] = s;
    }
    if (idx < E1 + E2) {
        int src = (idx < E1) ? e1[idx] : e2[idx - E1];
        atomicAdd(&cnt[src], 1);
    }
}

// one wave per node: s_src/s_dst dots; also writes bf16 copy of x (XBf)
__global__ void k_node_scores(const float* __restrict__ x, const float* __restrict__ vall,
                              float* __restrict__ s_src, float* __restrict__ s_dst,
                              __hip_bfloat16* __restrict__ XBf, int N) {
    int wid = (int)((blockIdx.x * (size_t)blockDim.x + threadIdx.x) >> 6);
    int lane = threadIdx.x & 63;
    if (wid >= N) return;
    const float* xp = x + (size_t)wid * 128;
    float x0 = xp[lane], x1 = xp[lane + 64];
    XBf[(size_t)wid * 128 + lane]      = __float2bfloat16(x0);
    XBf[(size_t)wid * 128 + 64 + lane] = __float2bfloat16(x1);
    float ps = x0 * vall[lane] + x1 * vall[lane + 64];
    float pd = x0 * vall[128 + lane] + x1 * vall[192 + lane];
    ps = waveReduceSum(ps);
    pd = waveReduceSum(pd);
    if (lane == 0) { s_src[wid] = ps; s_dst[wid] = pd; }
}

// single-block exclusive scan of cnt[N] -> start[N+1], cursor[N]
__global__ __launch_bounds__(1024) void k_scan_all(const int* __restrict__ cnt,
                                                   int* __restrict__ start,
                                                   int* __restrict__ cursor, int N) {
    __shared__ int wsum[16];
    int t = threadIdx.x;
    int lane = t & 63, wid = t >> 6;  // 16 waves
    int carry = 0;
    int nch = (N + 1023) / 1024;
    for (int c = 0; c < nch; ++c) {
        int idx = c * 1024 + t;
        int v = (idx < N) ? cnt[idx] : 0;
        int s = v;
#pragma unroll
        for (int off = 1; off < 64; off <<= 1) {
            int u = __shfl_up(s, off, 64);
            if (lane >= off) s += u;
        }
        if (lane == 63) wsum[wid] = s;
        __syncthreads();
        if (wid == 0) {
            int ws = (lane < 16) ? wsum[lane] : 0;
#pragma unroll
            for (int off = 1; off < 16; off <<= 1) {
                int u = __shfl_up(ws, off, 64);
                if (lane >= off) ws += u;
            }
            if (lane < 16) wsum[lane] = ws;  // inclusive prefix of wave sums
        }
        __syncthreads();
        int wprefix = (wid == 0) ? 0 : wsum[wid - 1];
        int total = wsum[15];
        int excl = s - v + wprefix + carry;
        if (idx < N) { start[idx] = excl; cursor[idx] = excl; }
        __syncthreads();  // protect wsum before next chunk
        carry += total;
    }
    if (t == 0) start[N] = carry;
}

// bucket edges by src: se[p] = (dst, e)
__global__ void k_scatter(const int* __restrict__ e1, int E1, const int* __restrict__ e2, int E2,
                          int* __restrict__ cursor, int2* __restrict__ se) {
    int e = blockIdx.x * blockDim.x + threadIdx.x;
    if (e >= E1 + E2) return;
    int src, dst;
    if (e < E1) { src = e1[e]; dst = e1[E1 + e]; }
    else { int t = e - E1; src = e2[t]; dst = e2[E2 + t]; }
    int p = atomicAdd(&cursor[src], 1);
    se[p] = make_int2(dst, e);
}

// one wave per node, FUSED, group-parallel (4 groups x 16 lanes, 8 edges/iter),
// with the HBM-latency stage (se -> emb row, s_dst) software-pipelined one
// iteration ahead. Cached XBf reads stay in the consume phase (VGPR budget).
__global__ void k_gather(const __hip_bfloat16* __restrict__ XBf,
                         const float* __restrict__ emb1, const float* __restrict__ emb2, int E1,
                         const int* __restrict__ start, const int2* __restrict__ se,
                         const float* __restrict__ vall,
                         const float* __restrict__ s_src, const float* __restrict__ s_dst,
                         __hip_bfloat16* __restrict__ G, float* __restrict__ sxf, int N) {
    int n = (int)((blockIdx.x * (size_t)blockDim.x + threadIdx.x) >> 6);
    int lane = threadIdx.x & 63;
    if (n >= N) return;
    n = __builtin_amdgcn_readfirstlane(n);
    int g = lane >> 4;   // edge slot within a 4-edge batch
    int t = lane & 15;   // lane within group
    int b = start[n], en = start[n + 1];
    float ssrc = s_src[n];
    f32x4 r4 = *reinterpret_cast<const f32x4*>(vall + 256 + 4 * t);
    f32x4 w4 = {0.f, 0.f, 0.f, 0.f};
    float u8[8] = {0.f, 0.f, 0.f, 0.f, 0.f, 0.f, 0.f, 0.f};
    float rs = 0.f;

    if (b < en) {
        f32x4 cem0, cem1;
        float csd0, csd1;
        int cd0x, cd1x;
        {   // prologue: stage loads for p = b
            int q0 = b + g, q1 = b + 4 + g;
            int c0 = (q0 < en) ? q0 : en - 1;
            int c1 = (q1 < en) ? q1 : en - 1;
            int2 d0 = se[c0], d1 = se[c1];
            const float* ep0 = (d0.y < E1) ? emb1 + (size_t)d0.y * 64 : emb2 + (size_t)(d0.y - E1) * 64;
            const float* ep1 = (d1.y < E1) ? emb1 + (size_t)d1.y * 64 : emb2 + (size_t)(d1.y - E1) * 64;
            cem0 = *reinterpret_cast<const f32x4*>(ep0 + 4 * t);
            cem1 = *reinterpret_cast<const f32x4*>(ep1 + 4 * t);
            csd0 = s_dst[d0.x]; csd1 = s_dst[d1.x];
            cd0x = d0.x; cd1x = d1.x;
        }
        for (int p = b; p < en; p += 8) {
            // stage next iteration's HBM loads (clamped; dead loads hit cache)
            f32x4 nem0, nem1;
            float nsd0, nsd1;
            int nd0x, nd1x;
            {
                int np = p + 8;
                int q0 = np + g, q1 = np + 4 + g;
                int c0 = (q0 < en) ? q0 : en - 1;
                int c1 = (q1 < en) ? q1 : en - 1;
                int2 d0 = se[c0], d1 = se[c1];
                const float* ep0 = (d0.y < E1) ? emb1 + (size_t)d0.y * 64 : emb2 + (size_t)(d0.y - E1) * 64;
                const float* ep1 = (d1.y < E1) ? emb1 + (size_t)d1.y * 64 : emb2 + (size_t)(d1.y - E1) * 64;
                nem0 = *reinterpret_cast<const f32x4*>(ep0 + 4 * t);
                nem1 = *reinterpret_cast<const f32x4*>(ep1 + 4 * t);
                nsd0 = s_dst[d0.x]; nsd1 = s_dst[d1.x];
                nd0x = d0.x; nd1x = d1.x;
            }
            // consume current
            bf16x8 xv0 = *reinterpret_cast<const bf16x8*>(XBf + (size_t)cd0x * 128 + 8 * t);
            bf16x8 xv1 = *reinterpret_cast<const bf16x8*>(XBf + (size_t)cd1x * 128 + 8 * t);
            float t0 = cem0.x * r4.x + cem0.y * r4.y + cem0.z * r4.z + cem0.w * r4.w;
            float t1 = cem1.x * r4.x + cem1.y * r4.y + cem1.z * r4.z + cem1.w * r4.w;
#pragma unroll
            for (int off = 1; off <= 8; off <<= 1) {
                t0 += __shfl_xor(t0, off, 64);
                t1 += __shfl_xor(t1, off, 64);
            }
            float sc0 = ssrc + csd0 + t0;
            float sc1 = ssrc + csd1 + t1;
            float pz0 = sc0 > 0.f ? sc0 : LRELU_ALPHA * sc0;
            float pz1 = sc1 > 0.f ? sc1 : LRELU_ALPHA * sc1;
            float e0 = __expf(-pz0);
            float e1v = __expf(-pz1);
            if (p + g >= en) e0 = 0.f;
            if (p + 4 + g >= en) e1v = 0.f;
            rs += e0 + e1v;
            w4 += e0 * cem0 + e1v * cem1;
#pragma unroll
            for (int j = 0; j < 8; ++j)
                u8[j] += e0 * (float)xv0[j] + e1v * (float)xv1[j];
            // rotate
            cem0 = nem0; cem1 = nem1; csd0 = nsd0; csd1 = nsd1; cd0x = nd0x; cd1x = nd1x;
        }
    }

    // combine the 4 per-group partials (once per node)
#pragma unroll
    for (int j = 0; j < 8; ++j) {
        u8[j] += __shfl_xor(u8[j], 16, 64);
        u8[j] += __shfl_xor(u8[j], 32, 64);
    }
#pragma unroll
    for (int j = 0; j < 4; ++j) {
        w4[j] += __shfl_xor(w4[j], 16, 64);
        w4[j] += __shfl_xor(w4[j], 32, 64);
    }
    rs += __shfl_xor(rs, 16, 64);
    rs += __shfl_xor(rs, 32, 64);

    float inv = (rs == 0.f) ? 0.f : 1.f / rs;
    if (lane < 16) {
        __hip_bfloat16* gp = G + (size_t)n * 192;
        bf16x8 uu;
#pragma unroll
        for (int j = 0; j < 8; ++j) uu[j] = (__bf16)(u8[j] * inv);
        *reinterpret_cast<bf16x8*>(gp + 8 * lane) = uu;
        bf16x4 ww;
#pragma unroll
        for (int j = 0; j < 4; ++j) ww[j] = (__bf16)(w4[j] * inv);
        *reinterpret_cast<bf16x4*>(gp + 128 + 4 * lane) = ww;
        if (lane == 0) sxf[n] = (rs == 0.f) ? 0.f : 1.f;
    }
}

// out[n][o] = elu( sxf[n] * (x[n].a_src[o] + G[n].[a_dst|a_rel][o]) ) via bf16 MFMA.
__global__ __launch_bounds__(256) void k_mfma(
    const __hip_bfloat16* __restrict__ XBf, const __hip_bfloat16* __restrict__ G,
    const __hip_bfloat16* __restrict__ ABf, const float* __restrict__ sxf,
    float* __restrict__ out, int N) {
    int lane = threadIdx.x & 63;
    int wave = threadIdx.x >> 6;
    int m0 = blockIdx.x * 64 + wave * 16;
    int q = lane >> 4, m = lane & 15;
    int rowm = m0 + m; if (rowm >= N) rowm = N - 1;  // clamp; garbage rows never stored
    const __hip_bfloat16* xr = XBf + (size_t)rowm * 128 + q * 8;
    const __hip_bfloat16* gr = G + (size_t)rowm * 192 + q * 8;
    const __hip_bfloat16* br = ABf + (size_t)m * 320 + q * 8;
    f32x4 acc[8];
#pragma unroll
    for (int c = 0; c < 8; ++c) acc[c] = f32x4{0.f, 0.f, 0.f, 0.f};

#pragma unroll
    for (int s = 0; s < 4; ++s) {  // k = s*32 .. +32 from XBf
        bf16x8 af = *reinterpret_cast<const bf16x8*>(xr + s * 32);
#pragma unroll
        for (int c = 0; c < 8; ++c) {
            bf16x8 bf = *reinterpret_cast<const bf16x8*>(br + (size_t)c * 16 * 320 + s * 32);
            acc[c] = __builtin_amdgcn_mfma_f32_16x16x32_bf16(af, bf, acc[c], 0, 0, 0);
        }
    }
#pragma unroll
    for (int s = 0; s < 6; ++s) {  // k = 128 + s*32 .. +32 from G
        bf16x8 af = *reinterpret_cast<const bf16x8*>(gr + s * 32);
#pragma unroll
        for (int c = 0; c < 8; ++c) {
            bf16x8 bf = *reinterpret_cast<const bf16x8*>(br + (size_t)c * 16 * 320 + 128 + s * 32);
            acc[c] = __builtin_amdgcn_mfma_f32_16x16x32_bf16(af, bf, acc[c], 0, 0, 0);
        }
    }

    float sxr[4];
#pragma unroll
    for (int r = 0; r < 4; ++r) {
        int n = m0 + q * 4 + r;
        sxr[r] = (n < N) ? sxf[n] : 0.f;
    }
#pragma unroll
    for (int c = 0; c < 8; ++c) {
#pragma unroll
        for (int r = 0; r < 4; ++r) {
            int n = m0 + q * 4 + r;
            if (n < N) {
                float h = acc[c][r] * sxr[r];
                out[(size_t)n * 128 + c * 16 + m] = h > 0.f ? h : __expf(h) - 1.f;
            }
        }
    }
}

extern "C" void kernel_launch(void* const* d_in, const int* in_sizes, int n_in,
                              void* d_out, int out_size, void* d_ws, size_t ws_size,
                              hipStream_t stream) {
    const float* x    = (const float*)d_in[0];
    const int*   e1   = (const int*)d_in[1];
    const float* emb1 = (const float*)d_in[2];
    const int*   e2   = (const int*)d_in[3];
    const float* emb2 = (const float*)d_in[4];
    const float* a    = (const float*)d_in[5];
    const float* a2   = (const float*)d_in[6];
    float* out = (float*)d_out;

    const int N  = in_sizes[0] / 128;
    const int E1 = in_sizes[1] / 2;
    const int E2 = in_sizes[3] / 2;
    const int E  = E1 + E2;

    // workspace layout
    float* ws    = (float*)d_ws;
    float* vall  = ws;                                   // 512 f
    __hip_bfloat16* ABf = (__hip_bfloat16*)(ws + 512);   // 128*320 bf16 = 20480 f
    float* s_src = ws + 512 + 20480;                     // N
    float* s_dst = s_src + N;                            // N
    float* sxf   = s_dst + N;                            // N
    int*   cnt    = (int*)(sxf + N);                     // N
    int*   bsum   = cnt + N;                             // 256 (reserved, unused)
    int*   start  = bsum + 256;                          // N+1
    int*   cursor = start + N + 1;                       // N+1
    size_t so = (size_t)((char*)(cursor + N + 1) - (char*)d_ws);
    so = (so + 15) & ~(size_t)15;
    int2*  se = (int2*)((char*)d_ws + so);               // E int2
    size_t xo = so + (size_t)E * sizeof(int2);
    xo = (xo + 15) & ~(size_t)15;
    __hip_bfloat16* XBf = (__hip_bfloat16*)((char*)d_ws + xo);  // N*128 bf16
    size_t go = xo + (size_t)N * 128 * sizeof(__hip_bfloat16);
    go = (go + 15) & ~(size_t)15;
    __hip_bfloat16* G = (__hip_bfloat16*)((char*)d_ws + go);    // N*192 bf16

    size_t needed = go + (size_t)N * 192 * sizeof(__hip_bfloat16);
    if (ws_size < needed) return;  // defensive

    hipMemsetAsync(cnt, 0, (size_t)N * sizeof(int), stream);

    int gridPC = ((E > 128 * 320 ? E : 128 * 320) + 255) / 256;
    k_prep_count<<<gridPC, 256, 0, stream>>>(a, a2, vall, ABf, e1, E1, e2, E2, cnt);
    k_node_scores<<<(N * 64 + 255) / 256, 256, 0, stream>>>(x, vall, s_src, s_dst, XBf, N);
    k_scan_all<<<1, 1024, 0, stream>>>(cnt, start, cursor, N);
    k_scatter<<<(E + 255) / 256, 256, 0, stream>>>(e1, E1, e2, E2, cursor, se);
    k_gather<<<(N * 64 + 255) / 256, 256, 0, stream>>>(
        XBf, emb1, emb2, E1, start, se, vall, s_src, s_dst, G, sxf, N);
    k_mfma<<<(N + 63) / 64, 256, 0, stream>>>(XBf, G, ABf, sxf, out, N);
}

// Round 3
// 541.408 us; speedup vs baseline: 1.1071x; 1.1071x over previous
//
#include <hip/hip_runtime.h>
#include <hip/hip_bf16.h>

#define LRELU_ALPHA 0.2f

typedef __bf16 bf16x8 __attribute__((ext_vector_type(8)));
typedef __bf16 bf16x4 __attribute__((ext_vector_type(4)));
typedef float f32x4 __attribute__((ext_vector_type(4)));

// Fused: ABf = bf16(a); vall[k] = sum_o a[o*320+k]*a2[o]; cnt[src]++ per edge.
__global__ void k_prep_count(const float* __restrict__ a, const float* __restrict__ a2,
                             float* __restrict__ vall, __hip_bfloat16* __restrict__ ABf,
                             const int* __restrict__ e1, int E1,
                             const int* __restrict__ e2, int E2, int* __restrict__ cnt) {
    int idx = blockIdx.x * 256 + threadIdx.x;
    if (idx < 128 * 320) ABf[idx] = __float2bfloat16(a[idx]);
    if (idx < 320) {
        float s = 0.f;
#pragma unroll 8
        for (int o = 0; o < 128; ++o) s += a[o * 320 + idx] * a2[o];
        vall[idx] = s;
    }
    if (idx < E1 + E2) {
        int src = (idx < E1) ? e1[idx] : e2[idx - E1];
        atomicAdd(&cnt[src], 1);
    }
}

// two nodes per wave (32 lanes each): f32x4 loads, 5-level reduce, bf16x4 XBf write.
__global__ void k_node_scores(const float* __restrict__ x, const float* __restrict__ vall,
                              float* __restrict__ s_src, float* __restrict__ s_dst,
                              __hip_bfloat16* __restrict__ XBf, int N) {
    int wid = (int)((blockIdx.x * (size_t)blockDim.x + threadIdx.x) >> 6);
    int lane = threadIdx.x & 63;
    if (wid * 2 >= N) return;
    int half = lane >> 5;
    int j = lane & 31;            // dim block: dims 4j..4j+3
    int n = wid * 2 + half;
    int nc = (n < N) ? n : N - 1;
    f32x4 xv = *reinterpret_cast<const f32x4*>(x + (size_t)nc * 128 + 4 * j);
    if (n < N) {
        bf16x4 xb;
#pragma unroll
        for (int k = 0; k < 4; ++k) xb[k] = (__bf16)xv[k];
        *reinterpret_cast<bf16x4*>(XBf + (size_t)n * 128 + 4 * j) = xb;
    }
    f32x4 vs = *reinterpret_cast<const f32x4*>(vall + 4 * j);
    f32x4 vd = *reinterpret_cast<const f32x4*>(vall + 128 + 4 * j);
    float ps = xv.x * vs.x + xv.y * vs.y + xv.z * vs.z + xv.w * vs.w;
    float pd = xv.x * vd.x + xv.y * vd.y + xv.z * vd.z + xv.w * vd.w;
#pragma unroll
    for (int off = 1; off <= 16; off <<= 1) {
        ps += __shfl_xor(ps, off, 64);
        pd += __shfl_xor(pd, off, 64);
    }
    if (j == 0 && n < N) { s_src[n] = ps; s_dst[n] = pd; }
}

// hierarchical exclusive scan of cnt[N] -> start[N+1], cursor[N]  (proven 3-kernel)
__global__ void k_scan1(const int* __restrict__ cnt, int* __restrict__ bsum, int N) {
    __shared__ int red[256];
    int t = threadIdx.x;
    int idx = blockIdx.x * 256 + t;
    red[t] = (idx < N) ? cnt[idx] : 0;
    __syncthreads();
    for (int off = 128; off > 0; off >>= 1) {
        if (t < off) red[t] += red[t + off];
        __syncthreads();
    }
    if (t == 0) bsum[blockIdx.x] = red[0];
}

__global__ void k_scan2(int* __restrict__ bsum, int nb) {
    __shared__ int tmp[256];
    int t = threadIdx.x;
    int v = (t < nb) ? bsum[t] : 0;
    tmp[t] = v;
    __syncthreads();
    for (int off = 1; off < 256; off <<= 1) {
        int add = (t >= off) ? tmp[t - off] : 0;
        __syncthreads();
        tmp[t] += add;
        __syncthreads();
    }
    if (t < nb) bsum[t] = tmp[t] - v;  // exclusive
}

__global__ void k_scan3(const int* __restrict__ cnt, const int* __restrict__ bsum,
                        int* __restrict__ start, int* __restrict__ cursor, int N, int E) {
    __shared__ int tmp[256];
    int t = threadIdx.x;
    int idx = blockIdx.x * 256 + t;
    int v = (idx < N) ? cnt[idx] : 0;
    tmp[t] = v;
    __syncthreads();
    for (int off = 1; off < 256; off <<= 1) {
        int add = (t >= off) ? tmp[t - off] : 0;
        __syncthreads();
        tmp[t] += add;
        __syncthreads();
    }
    if (idx < N) {
        int excl = tmp[t] - v + bsum[blockIdx.x];
        start[idx] = excl;
        cursor[idx] = excl;
    }
    if (blockIdx.x == 0 && t == 0) start[N] = E;
}

// bucket edges by src: se[p] = (dst, e)
__global__ void k_scatter(const int* __restrict__ e1, int E1, const int* __restrict__ e2, int E2,
                          int* __restrict__ cursor, int2* __restrict__ se) {
    int e = blockIdx.x * blockDim.x + threadIdx.x;
    if (e >= E1 + E2) return;
    int src, dst;
    if (e < E1) { src = e1[e]; dst = e1[E1 + e]; }
    else { int t = e - E1; src = e2[t]; dst = e2[E2 + t]; }
    int p = atomicAdd(&cursor[src], 1);
    se[p] = make_int2(dst, e);
}

// one wave per node, FUSED, group-parallel: 4 groups of 16 lanes, 8 edges/iter.
// emb row = f32x4/lane (dwordx4), dst x row = bf16x8/lane. u/w accumulators are
// per-group partials over all dims; combined across groups once per node.
// (round-1 proven version; pipelining confirmed neutral-to-negative —
//  gather is at the random-256B-read DRAM row-activation floor ~2.6 TB/s)
__global__ void k_gather(const __hip_bfloat16* __restrict__ XBf,
                         const float* __restrict__ emb1, const float* __restrict__ emb2, int E1,
                         const int* __restrict__ start, const int2* __restrict__ se,
                         const float* __restrict__ vall,
                         const float* __restrict__ s_src, const float* __restrict__ s_dst,
                         __hip_bfloat16* __restrict__ G, float* __restrict__ sxf, int N) {
    int n = (int)((blockIdx.x * (size_t)blockDim.x + threadIdx.x) >> 6);
    int lane = threadIdx.x & 63;
    if (n >= N) return;
    n = __builtin_amdgcn_readfirstlane(n);
    int g = lane >> 4;   // edge slot within a 4-edge batch
    int t = lane & 15;   // lane within group
    int b = start[n], en = start[n + 1];
    float ssrc = s_src[n];
    f32x4 r4 = *reinterpret_cast<const f32x4*>(vall + 256 + 4 * t);
    f32x4 w4 = {0.f, 0.f, 0.f, 0.f};
    float u8[8] = {0.f, 0.f, 0.f, 0.f, 0.f, 0.f, 0.f, 0.f};
    float rs = 0.f;

    for (int p = b; p < en; p += 8) {
        int q0 = p + g;
        int q1 = p + 4 + g;
        int c0 = (q0 < en) ? q0 : en - 1;   // en > b here, so en-1 valid
        int c1 = (q1 < en) ? q1 : en - 1;
        int2 d0 = se[c0];
        int2 d1 = se[c1];
        const float* ep0 = (d0.y < E1) ? emb1 + (size_t)d0.y * 64 : emb2 + (size_t)(d0.y - E1) * 64;
        const float* ep1 = (d1.y < E1) ? emb1 + (size_t)d1.y * 64 : emb2 + (size_t)(d1.y - E1) * 64;
        f32x4 em0 = *reinterpret_cast<const f32x4*>(ep0 + 4 * t);
        f32x4 em1 = *reinterpret_cast<const f32x4*>(ep1 + 4 * t);
        bf16x8 xv0 = *reinterpret_cast<const bf16x8*>(XBf + (size_t)d0.x * 128 + 8 * t);
        bf16x8 xv1 = *reinterpret_cast<const bf16x8*>(XBf + (size_t)d1.x * 128 + 8 * t);
        float sd0 = s_dst[d0.x], sd1 = s_dst[d1.x];
        float t0 = em0.x * r4.x + em0.y * r4.y + em0.z * r4.z + em0.w * r4.w;
        float t1 = em1.x * r4.x + em1.y * r4.y + em1.z * r4.z + em1.w * r4.w;
#pragma unroll
        for (int off = 1; off <= 8; off <<= 1) {
            t0 += __shfl_xor(t0, off, 64);
            t1 += __shfl_xor(t1, off, 64);
        }
        float sc0 = ssrc + sd0 + t0;
        float sc1 = ssrc + sd1 + t1;
        float pz0 = sc0 > 0.f ? sc0 : LRELU_ALPHA * sc0;
        float pz1 = sc1 > 0.f ? sc1 : LRELU_ALPHA * sc1;
        float e0 = __expf(-pz0);
        float e1v = __expf(-pz1);
        if (q0 >= en) e0 = 0.f;
        if (q1 >= en) e1v = 0.f;
        rs += e0 + e1v;
        w4 += e0 * em0 + e1v * em1;
#pragma unroll
        for (int j = 0; j < 8; ++j)
            u8[j] += e0 * (float)xv0[j] + e1v * (float)xv1[j];
    }

    // combine the 4 per-group partials (once per node)
#pragma unroll
    for (int j = 0; j < 8; ++j) {
        u8[j] += __shfl_xor(u8[j], 16, 64);
        u8[j] += __shfl_xor(u8[j], 32, 64);
    }
#pragma unroll
    for (int j = 0; j < 4; ++j) {
        w4[j] += __shfl_xor(w4[j], 16, 64);
        w4[j] += __shfl_xor(w4[j], 32, 64);
    }
    rs += __shfl_xor(rs, 16, 64);
    rs += __shfl_xor(rs, 32, 64);

    float inv = (rs == 0.f) ? 0.f : 1.f / rs;
    if (lane < 16) {
        __hip_bfloat16* gp = G + (size_t)n * 192;
        bf16x8 uu;
#pragma unroll
        for (int j = 0; j < 8; ++j) uu[j] = (__bf16)(u8[j] * inv);
        *reinterpret_cast<bf16x8*>(gp + 8 * lane) = uu;
        bf16x4 ww;
#pragma unroll
        for (int j = 0; j < 4; ++j) ww[j] = (__bf16)(w4[j] * inv);
        *reinterpret_cast<bf16x4*>(gp + 128 + 4 * lane) = ww;
        if (lane == 0) sxf[n] = (rs == 0.f) ? 0.f : 1.f;
    }
}

// out[n][o] = elu( sxf[n] * (x[n].a_src[o] + G[n].[a_dst|a_rel][o]) ) via bf16 MFMA.
__global__ __launch_bounds__(256) void k_mfma(
    const __hip_bfloat16* __restrict__ XBf, const __hip_bfloat16* __restrict__ G,
    const __hip_bfloat16* __restrict__ ABf, const float* __restrict__ sxf,
    float* __restrict__ out, int N) {
    int lane = threadIdx.x & 63;
    int wave = threadIdx.x >> 6;
    int m0 = blockIdx.x * 64 + wave * 16;
    int q = lane >> 4, m = lane & 15;
    int rowm = m0 + m; if (rowm >= N) rowm = N - 1;  // clamp; garbage rows never stored
    const __hip_bfloat16* xr = XBf + (size_t)rowm * 128 + q * 8;
    const __hip_bfloat16* gr = G + (size_t)rowm * 192 + q * 8;
    const __hip_bfloat16* br = ABf + (size_t)m * 320 + q * 8;
    f32x4 acc[8];
#pragma unroll
    for (int c = 0; c < 8; ++c) acc[c] = f32x4{0.f, 0.f, 0.f, 0.f};

#pragma unroll
    for (int s = 0; s < 4; ++s) {  // k = s*32 .. +32 from XBf
        bf16x8 af = *reinterpret_cast<const bf16x8*>(xr + s * 32);
#pragma unroll
        for (int c = 0; c < 8; ++c) {
            bf16x8 bf = *reinterpret_cast<const bf16x8*>(br + (size_t)c * 16 * 320 + s * 32);
            acc[c] = __builtin_amdgcn_mfma_f32_16x16x32_bf16(af, bf, acc[c], 0, 0, 0);
        }
    }
#pragma unroll
    for (int s = 0; s < 6; ++s) {  // k = 128 + s*32 .. +32 from G
        bf16x8 af = *reinterpret_cast<const bf16x8*>(gr + s * 32);
#pragma unroll
        for (int c = 0; c < 8; ++c) {
            bf16x8 bf = *reinterpret_cast<const bf16x8*>(br + (size_t)c * 16 * 320 + 128 + s * 32);
            acc[c] = __builtin_amdgcn_mfma_f32_16x16x32_bf16(af, bf, acc[c], 0, 0, 0);
        }
    }

    float sxr[4];
#pragma unroll
    for (int r = 0; r < 4; ++r) {
        int n = m0 + q * 4 + r;
        sxr[r] = (n < N) ? sxf[n] : 0.f;
    }
#pragma unroll
    for (int c = 0; c < 8; ++c) {
#pragma unroll
        for (int r = 0; r < 4; ++r) {
            int n = m0 + q * 4 + r;
            if (n < N) {
                float h = acc[c][r] * sxr[r];
                out[(size_t)n * 128 + c * 16 + m] = h > 0.f ? h : __expf(h) - 1.f;
            }
        }
    }
}

extern "C" void kernel_launch(void* const* d_in, const int* in_sizes, int n_in,
                              void* d_out, int out_size, void* d_ws, size_t ws_size,
                              hipStream_t stream) {
    const float* x    = (const float*)d_in[0];
    const int*   e1   = (const int*)d_in[1];
    const float* emb1 = (const float*)d_in[2];
    const int*   e2   = (const int*)d_in[3];
    const float* emb2 = (const float*)d_in[4];
    const float* a    = (const float*)d_in[5];
    const float* a2   = (const float*)d_in[6];
    float* out = (float*)d_out;

    const int N  = in_sizes[0] / 128;
    const int E1 = in_sizes[1] / 2;
    const int E2 = in_sizes[3] / 2;
    const int E  = E1 + E2;
    const int NB = (N + 255) / 256;  // <=256 (N<=65536)

    // workspace layout
    float* ws    = (float*)d_ws;
    float* vall  = ws;                                   // 512 f
    __hip_bfloat16* ABf = (__hip_bfloat16*)(ws + 512);   // 128*320 bf16 = 20480 f
    float* s_src = ws + 512 + 20480;                     // N
    float* s_dst = s_src + N;                            // N
    float* sxf   = s_dst + N;                            // N
    int*   cnt    = (int*)(sxf + N);                     // N
    int*   bsum   = cnt + N;                             // 256
    int*   start  = bsum + 256;                          // N+1
    int*   cursor = start + N + 1;                       // N+1
    size_t so = (size_t)((char*)(cursor + N + 1) - (char*)d_ws);
    so = (so + 15) & ~(size_t)15;
    int2*  se = (int2*)((char*)d_ws + so);               // E int2
    size_t xo = so + (size_t)E * sizeof(int2);
    xo = (xo + 15) & ~(size_t)15;
    __hip_bfloat16* XBf = (__hip_bfloat16*)((char*)d_ws + xo);  // N*128 bf16
    size_t go = xo + (size_t)N * 128 * sizeof(__hip_bfloat16);
    go = (go + 15) & ~(size_t)15;
    __hip_bfloat16* G = (__hip_bfloat16*)((char*)d_ws + go);    // N*192 bf16

    size_t needed = go + (size_t)N * 192 * sizeof(__hip_bfloat16);
    if (ws_size < needed) return;  // defensive

    hipMemsetAsync(cnt, 0, (size_t)N * sizeof(int), stream);

    int gridPC = ((E > 128 * 320 ? E : 128 * 320) + 255) / 256;
    k_prep_count<<<gridPC, 256, 0, stream>>>(a, a2, vall, ABf, e1, E1, e2, E2, cnt);
    int W = (N + 1) / 2;  // waves for node_scores (2 nodes/wave)
    k_node_scores<<<(W * 64 + 255) / 256, 256, 0, stream>>>(x, vall, s_src, s_dst, XBf, N);
    k_scan1<<<NB, 256, 0, stream>>>(cnt, bsum, N);
    k_scan2<<<1, 256, 0, stream>>>(bsum, NB);
    k_scan3<<<NB, 256, 0, stream>>>(cnt, bsum, start, cursor, N, E);
    k_scatter<<<(E + 255) / 256, 256, 0, stream>>>(e1, E1, e2, E2, cursor, se);
    k_gather<<<(N * 64 + 255) / 256, 256, 0, stream>>>(
        XBf, emb1, emb2, E1, start, se, vall, s_src, s_dst, G, sxf, N);
    k_mfma<<<(N + 63) / 64, 256, 0, stream>>>(XBf, G, ABf, sxf, out, N);
}

// Round 4
// 537.199 us; speedup vs baseline: 1.1158x; 1.0078x over previous
//
#include <hip/hip_runtime.h>
#include <hip/hip_bf16.h>

#define LRELU_ALPHA 0.2f

typedef __bf16 bf16x8 __attribute__((ext_vector_type(8)));
typedef __bf16 bf16x4 __attribute__((ext_vector_type(4)));
typedef float f32x4 __attribute__((ext_vector_type(4)));

// Fused: ABf = bf16(a); vall[k] = sum_o a[o*320+k]*a2[o]; cnt[src]++ per edge.
__global__ void k_prep_count(const float* __restrict__ a, const float* __restrict__ a2,
                             float* __restrict__ vall, __hip_bfloat16* __restrict__ ABf,
                             const int* __restrict__ e1, int E1,
                             const int* __restrict__ e2, int E2, int* __restrict__ cnt) {
    int idx = blockIdx.x * 256 + threadIdx.x;
    if (idx < 128 * 320) ABf[idx] = __float2bfloat16(a[idx]);
    if (idx < 320) {
        float s = 0.f;
#pragma unroll 8
        for (int o = 0; o < 128; ++o) s += a[o * 320 + idx] * a2[o];
        vall[idx] = s;
    }
    if (idx < E1 + E2) {
        int src = (idx < E1) ? e1[idx] : e2[idx - E1];
        atomicAdd(&cnt[src], 1);
    }
}

// two nodes per wave (32 lanes each): f32x4 loads, 5-level reduce, bf16x4 XBf write.
__global__ void k_node_scores(const float* __restrict__ x, const float* __restrict__ vall,
                              float* __restrict__ s_src, float* __restrict__ s_dst,
                              __hip_bfloat16* __restrict__ XBf, int N) {
    int wid = (int)((blockIdx.x * (size_t)blockDim.x + threadIdx.x) >> 6);
    int lane = threadIdx.x & 63;
    if (wid * 2 >= N) return;
    int half = lane >> 5;
    int j = lane & 31;            // dim block: dims 4j..4j+3
    int n = wid * 2 + half;
    int nc = (n < N) ? n : N - 1;
    f32x4 xv = *reinterpret_cast<const f32x4*>(x + (size_t)nc * 128 + 4 * j);
    if (n < N) {
        bf16x4 xb;
#pragma unroll
        for (int k = 0; k < 4; ++k) xb[k] = (__bf16)xv[k];
        *reinterpret_cast<bf16x4*>(XBf + (size_t)n * 128 + 4 * j) = xb;
    }
    f32x4 vs = *reinterpret_cast<const f32x4*>(vall + 4 * j);
    f32x4 vd = *reinterpret_cast<const f32x4*>(vall + 128 + 4 * j);
    float ps = xv.x * vs.x + xv.y * vs.y + xv.z * vs.z + xv.w * vs.w;
    float pd = xv.x * vd.x + xv.y * vd.y + xv.z * vd.z + xv.w * vd.w;
#pragma unroll
    for (int off = 1; off <= 16; off <<= 1) {
        ps += __shfl_xor(ps, off, 64);
        pd += __shfl_xor(pd, off, 64);
    }
    if (j == 0 && n < N) { s_src[n] = ps; s_dst[n] = pd; }
}

// hierarchical exclusive scan of cnt[N] -> start[N+1], cursor[N]  (proven 3-kernel)
__global__ void k_scan1(const int* __restrict__ cnt, int* __restrict__ bsum, int N) {
    __shared__ int red[256];
    int t = threadIdx.x;
    int idx = blockIdx.x * 256 + t;
    red[t] = (idx < N) ? cnt[idx] : 0;
    __syncthreads();
    for (int off = 128; off > 0; off >>= 1) {
        if (t < off) red[t] += red[t + off];
        __syncthreads();
    }
    if (t == 0) bsum[blockIdx.x] = red[0];
}

__global__ void k_scan2(int* __restrict__ bsum, int nb) {
    __shared__ int tmp[256];
    int t = threadIdx.x;
    int v = (t < nb) ? bsum[t] : 0;
    tmp[t] = v;
    __syncthreads();
    for (int off = 1; off < 256; off <<= 1) {
        int add = (t >= off) ? tmp[t - off] : 0;
        __syncthreads();
        tmp[t] += add;
        __syncthreads();
    }
    if (t < nb) bsum[t] = tmp[t] - v;  // exclusive
}

__global__ void k_scan3(const int* __restrict__ cnt, const int* __restrict__ bsum,
                        int* __restrict__ start, int* __restrict__ cursor, int N, int E) {
    __shared__ int tmp[256];
    int t = threadIdx.x;
    int idx = blockIdx.x * 256 + t;
    int v = (idx < N) ? cnt[idx] : 0;
    tmp[t] = v;
    __syncthreads();
    for (int off = 1; off < 256; off <<= 1) {
        int add = (t >= off) ? tmp[t - off] : 0;
        __syncthreads();
        tmp[t] += add;
        __syncthreads();
    }
    if (idx < N) {
        int excl = tmp[t] - v + bsum[blockIdx.x];
        start[idx] = excl;
        cursor[idx] = excl;
    }
    if (blockIdx.x == 0 && t == 0) start[N] = E;
}

// Bucketing WITH payload relocation: one 16-lane group per edge.
// Linear read of emb row (f32x4/lane), linear edge reads; random 128 B bf16
// row write to embS[p], plus sd[p]=dst and tS[p]=emb.a_rel (f32 dot, same
// reduce tree as before -> score numerics unchanged).
__global__ void k_scatter_copy(const int* __restrict__ e1, int E1,
                               const int* __restrict__ e2, int E2,
                               int* __restrict__ cursor,
                               const float* __restrict__ emb1, const float* __restrict__ emb2,
                               const float* __restrict__ vall,
                               int* __restrict__ sd, float* __restrict__ tS,
                               __hip_bfloat16* __restrict__ embS) {
    int wid = (int)((blockIdx.x * (size_t)blockDim.x + threadIdx.x) >> 6);
    int lane = threadIdx.x & 63;
    int g = lane >> 4, t = lane & 15;
    int e = wid * 4 + g;
    int E = E1 + E2;
    if (e >= E) return;
    int src, dst;
    const float* ep;
    if (e < E1) { src = e1[e]; dst = e1[E1 + e]; ep = emb1 + (size_t)e * 64; }
    else { int q = e - E1; src = e2[q]; dst = e2[E2 + q]; ep = emb2 + (size_t)q * 64; }
    f32x4 em = *reinterpret_cast<const f32x4*>(ep + 4 * t);
    f32x4 r4 = *reinterpret_cast<const f32x4*>(vall + 256 + 4 * t);
    float tv = em.x * r4.x + em.y * r4.y + em.z * r4.z + em.w * r4.w;
#pragma unroll
    for (int off = 1; off <= 8; off <<= 1) tv += __shfl_xor(tv, off, 64);
    int p = 0;
    if (t == 0) p = atomicAdd(&cursor[src], 1);
    p = __shfl(p, g * 16, 64);  // broadcast from group leader
    bf16x4 eb;
#pragma unroll
    for (int k = 0; k < 4; ++k) eb[k] = (__bf16)em[k];
    *reinterpret_cast<bf16x4*>(embS + (size_t)p * 64 + 4 * t) = eb;
    if (t == 0) { sd[p] = dst; tS[p] = tv; }
}

// one wave per node, group-parallel (4 groups x 16 lanes, 8 edges/iter).
// All per-edge streams (sd, tS, embS) are now LINEAR within the node's segment;
// only XBf reads are random (L3-resident, 12.8 MB). No per-edge shfl chain.
__global__ void k_gather(const __hip_bfloat16* __restrict__ XBf,
                         const __hip_bfloat16* __restrict__ embS,
                         const float* __restrict__ tS, const int* __restrict__ sd,
                         const int* __restrict__ start,
                         const float* __restrict__ s_src, const float* __restrict__ s_dst,
                         __hip_bfloat16* __restrict__ G, float* __restrict__ sxf, int N) {
    int n = (int)((blockIdx.x * (size_t)blockDim.x + threadIdx.x) >> 6);
    int lane = threadIdx.x & 63;
    if (n >= N) return;
    n = __builtin_amdgcn_readfirstlane(n);
    int g = lane >> 4;   // edge slot within a 4-edge batch
    int t = lane & 15;   // lane within group
    int b = start[n], en = start[n + 1];
    float ssrc = s_src[n];
    f32x4 w4 = {0.f, 0.f, 0.f, 0.f};
    float u8[8] = {0.f, 0.f, 0.f, 0.f, 0.f, 0.f, 0.f, 0.f};
    float rs = 0.f;

    for (int p = b; p < en; p += 8) {
        int q0 = p + g;
        int q1 = p + 4 + g;
        int c0 = (q0 < en) ? q0 : en - 1;   // en > b here, so en-1 valid
        int c1 = (q1 < en) ? q1 : en - 1;
        int d0 = sd[c0], d1 = sd[c1];
        float t0 = tS[c0], t1 = tS[c1];
        bf16x4 ev0 = *reinterpret_cast<const bf16x4*>(embS + (size_t)c0 * 64 + 4 * t);
        bf16x4 ev1 = *reinterpret_cast<const bf16x4*>(embS + (size_t)c1 * 64 + 4 * t);
        bf16x8 xv0 = *reinterpret_cast<const bf16x8*>(XBf + (size_t)d0 * 128 + 8 * t);
        bf16x8 xv1 = *reinterpret_cast<const bf16x8*>(XBf + (size_t)d1 * 128 + 8 * t);
        float sd0 = s_dst[d0], sd1 = s_dst[d1];
        float sc0 = ssrc + sd0 + t0;
        float sc1 = ssrc + sd1 + t1;
        float pz0 = sc0 > 0.f ? sc0 : LRELU_ALPHA * sc0;
        float pz1 = sc1 > 0.f ? sc1 : LRELU_ALPHA * sc1;
        float e0 = __expf(-pz0);
        float e1v = __expf(-pz1);
        if (q0 >= en) e0 = 0.f;
        if (q1 >= en) e1v = 0.f;
        rs += e0 + e1v;
        f32x4 f0 = {(float)ev0[0], (float)ev0[1], (float)ev0[2], (float)ev0[3]};
        f32x4 f1 = {(float)ev1[0], (float)ev1[1], (float)ev1[2], (float)ev1[3]};
        w4 += e0 * f0 + e1v * f1;
#pragma unroll
        for (int j = 0; j < 8; ++j)
            u8[j] += e0 * (float)xv0[j] + e1v * (float)xv1[j];
    }

    // combine the 4 per-group partials (once per node)
#pragma unroll
    for (int j = 0; j < 8; ++j) {
        u8[j] += __shfl_xor(u8[j], 16, 64);
        u8[j] += __shfl_xor(u8[j], 32, 64);
    }
#pragma unroll
    for (int j = 0; j < 4; ++j) {
        w4[j] += __shfl_xor(w4[j], 16, 64);
        w4[j] += __shfl_xor(w4[j], 32, 64);
    }
    rs += __shfl_xor(rs, 16, 64);
    rs += __shfl_xor(rs, 32, 64);

    float inv = (rs == 0.f) ? 0.f : 1.f / rs;
    if (lane < 16) {
        __hip_bfloat16* gp = G + (size_t)n * 192;
        bf16x8 uu;
#pragma unroll
        for (int j = 0; j < 8; ++j) uu[j] = (__bf16)(u8[j] * inv);
        *reinterpret_cast<bf16x8*>(gp + 8 * lane) = uu;
        bf16x4 ww;
#pragma unroll
        for (int j = 0; j < 4; ++j) ww[j] = (__bf16)(w4[j] * inv);
        *reinterpret_cast<bf16x4*>(gp + 128 + 4 * lane) = ww;
        if (lane == 0) sxf[n] = (rs == 0.f) ? 0.f : 1.f;
    }
}

// out[n][o] = elu( sxf[n] * (x[n].a_src[o] + G[n].[a_dst|a_rel][o]) ) via bf16 MFMA.
__global__ __launch_bounds__(256) void k_mfma(
    const __hip_bfloat16* __restrict__ XBf, const __hip_bfloat16* __restrict__ G,
    const __hip_bfloat16* __restrict__ ABf, const float* __restrict__ sxf,
    float* __restrict__ out, int N) {
    int lane = threadIdx.x & 63;
    int wave = threadIdx.x >> 6;
    int m0 = blockIdx.x * 64 + wave * 16;
    int q = lane >> 4, m = lane & 15;
    int rowm = m0 + m; if (rowm >= N) rowm = N - 1;  // clamp; garbage rows never stored
    const __hip_bfloat16* xr = XBf + (size_t)rowm * 128 + q * 8;
    const __hip_bfloat16* gr = G + (size_t)rowm * 192 + q * 8;
    const __hip_bfloat16* br = ABf + (size_t)m * 320 + q * 8;
    f32x4 acc[8];
#pragma unroll
    for (int c = 0; c < 8; ++c) acc[c] = f32x4{0.f, 0.f, 0.f, 0.f};

#pragma unroll
    for (int s = 0; s < 4; ++s) {  // k = s*32 .. +32 from XBf
        bf16x8 af = *reinterpret_cast<const bf16x8*>(xr + s * 32);
#pragma unroll
        for (int c = 0; c < 8; ++c) {
            bf16x8 bf = *reinterpret_cast<const bf16x8*>(br + (size_t)c * 16 * 320 + s * 32);
            acc[c] = __builtin_amdgcn_mfma_f32_16x16x32_bf16(af, bf, acc[c], 0, 0, 0);
        }
    }
#pragma unroll
    for (int s = 0; s < 6; ++s) {  // k = 128 + s*32 .. +32 from G
        bf16x8 af = *reinterpret_cast<const bf16x8*>(gr + s * 32);
#pragma unroll
        for (int c = 0; c < 8; ++c) {
            bf16x8 bf = *reinterpret_cast<const bf16x8*>(br + (size_t)c * 16 * 320 + 128 + s * 32);
            acc[c] = __builtin_amdgcn_mfma_f32_16x16x32_bf16(af, bf, acc[c], 0, 0, 0);
        }
    }

    float sxr[4];
#pragma unroll
    for (int r = 0; r < 4; ++r) {
        int n = m0 + q * 4 + r;
        sxr[r] = (n < N) ? sxf[n] : 0.f;
    }
#pragma unroll
    for (int c = 0; c < 8; ++c) {
#pragma unroll
        for (int r = 0; r < 4; ++r) {
            int n = m0 + q * 4 + r;
            if (n < N) {
                float h = acc[c][r] * sxr[r];
                out[(size_t)n * 128 + c * 16 + m] = h > 0.f ? h : __expf(h) - 1.f;
            }
        }
    }
}

extern "C" void kernel_launch(void* const* d_in, const int* in_sizes, int n_in,
                              void* d_out, int out_size, void* d_ws, size_t ws_size,
                              hipStream_t stream) {
    const float* x    = (const float*)d_in[0];
    const int*   e1   = (const int*)d_in[1];
    const float* emb1 = (const float*)d_in[2];
    const int*   e2   = (const int*)d_in[3];
    const float* emb2 = (const float*)d_in[4];
    const float* a    = (const float*)d_in[5];
    const float* a2   = (const float*)d_in[6];
    float* out = (float*)d_out;

    const int N  = in_sizes[0] / 128;
    const int E1 = in_sizes[1] / 2;
    const int E2 = in_sizes[3] / 2;
    const int E  = E1 + E2;
    const int NB = (N + 255) / 256;  // <=256 (N<=65536)

    // workspace layout
    float* ws    = (float*)d_ws;
    float* vall  = ws;                                   // 512 f
    __hip_bfloat16* ABf = (__hip_bfloat16*)(ws + 512);   // 128*320 bf16 = 20480 f
    float* s_src = ws + 512 + 20480;                     // N
    float* s_dst = s_src + N;                            // N
    float* sxf   = s_dst + N;                            // N
    int*   cnt    = (int*)(sxf + N);                     // N
    int*   bsum   = cnt + N;                             // 256
    int*   start  = bsum + 256;                          // N+1
    int*   cursor = start + N + 1;                       // N+1
    int*   sd     = cursor + N + 1;                      // E
    float* tS     = (float*)(sd + E);                    // E
    size_t so = (size_t)((char*)(tS + E) - (char*)d_ws);
    so = (so + 127) & ~(size_t)127;
    __hip_bfloat16* embS = (__hip_bfloat16*)((char*)d_ws + so);  // E*64 bf16 = 128 B/row
    size_t xo = so + (size_t)E * 64 * sizeof(__hip_bfloat16);
    xo = (xo + 15) & ~(size_t)15;
    __hip_bfloat16* XBf = (__hip_bfloat16*)((char*)d_ws + xo);  // N*128 bf16
    size_t go = xo + (size_t)N * 128 * sizeof(__hip_bfloat16);
    go = (go + 15) & ~(size_t)15;
    __hip_bfloat16* G = (__hip_bfloat16*)((char*)d_ws + go);    // N*192 bf16

    size_t needed = go + (size_t)N * 192 * sizeof(__hip_bfloat16);
    if (ws_size < needed) return;  // defensive

    hipMemsetAsync(cnt, 0, (size_t)N * sizeof(int), stream);

    int gridPC = ((E > 128 * 320 ? E : 128 * 320) + 255) / 256;
    k_prep_count<<<gridPC, 256, 0, stream>>>(a, a2, vall, ABf, e1, E1, e2, E2, cnt);
    int W = (N + 1) / 2;  // waves for node_scores (2 nodes/wave)
    k_node_scores<<<(W * 64 + 255) / 256, 256, 0, stream>>>(x, vall, s_src, s_dst, XBf, N);
    k_scan1<<<NB, 256, 0, stream>>>(cnt, bsum, N);
    k_scan2<<<1, 256, 0, stream>>>(bsum, NB);
    k_scan3<<<NB, 256, 0, stream>>>(cnt, bsum, start, cursor, N, E);
    int Wsc = (E + 3) / 4;  // waves for scatter_copy (4 edges/wave)
    k_scatter_copy<<<(Wsc * 64 + 255) / 256, 256, 0, stream>>>(
        e1, E1, e2, E2, cursor, emb1, emb2, vall, sd, tS, embS);
    k_gather<<<(N * 64 + 255) / 256, 256, 0, stream>>>(
        XBf, embS, tS, sd, start, s_src, s_dst, G, sxf, N);
    k_mfma<<<(N + 63) / 64, 256, 0, stream>>>(XBf, G, ABf, sxf, out, N);
}

// Round 5
// 528.489 us; speedup vs baseline: 1.1342x; 1.0165x over previous
//
#include <hip/hip_runtime.h>
#include <hip/hip_bf16.h>

#define LRELU_ALPHA 0.2f

typedef __bf16 bf16x8 __attribute__((ext_vector_type(8)));
typedef __bf16 bf16x4 __attribute__((ext_vector_type(4)));
typedef float f32x4 __attribute__((ext_vector_type(4)));

// Fused: ABf = bf16(a); vall[k] = sum_o a[o*320+k]*a2[o]; cnt[src]++ per edge.
__global__ void k_prep_count(const float* __restrict__ a, const float* __restrict__ a2,
                             float* __restrict__ vall, __hip_bfloat16* __restrict__ ABf,
                             const int* __restrict__ e1, int E1,
                             const int* __restrict__ e2, int E2, int* __restrict__ cnt) {
    int idx = blockIdx.x * 256 + threadIdx.x;
    if (idx < 128 * 320) ABf[idx] = __float2bfloat16(a[idx]);
    if (idx < 320) {
        float s = 0.f;
#pragma unroll 8
        for (int o = 0; o < 128; ++o) s += a[o * 320 + idx] * a2[o];
        vall[idx] = s;
    }
    if (idx < E1 + E2) {
        int src = (idx < E1) ? e1[idx] : e2[idx - E1];
        atomicAdd(&cnt[src], 1);
    }
}

// two nodes per wave (32 lanes each): f32x4 loads, 5-level reduce, bf16x4 XBf write.
__global__ void k_node_scores(const float* __restrict__ x, const float* __restrict__ vall,
                              float* __restrict__ s_src, float* __restrict__ s_dst,
                              __hip_bfloat16* __restrict__ XBf, int N) {
    int wid = (int)((blockIdx.x * (size_t)blockDim.x + threadIdx.x) >> 6);
    int lane = threadIdx.x & 63;
    if (wid * 2 >= N) return;
    int half = lane >> 5;
    int j = lane & 31;            // dim block: dims 4j..4j+3
    int n = wid * 2 + half;
    int nc = (n < N) ? n : N - 1;
    f32x4 xv = *reinterpret_cast<const f32x4*>(x + (size_t)nc * 128 + 4 * j);
    if (n < N) {
        bf16x4 xb;
#pragma unroll
        for (int k = 0; k < 4; ++k) xb[k] = (__bf16)xv[k];
        *reinterpret_cast<bf16x4*>(XBf + (size_t)n * 128 + 4 * j) = xb;
    }
    f32x4 vs = *reinterpret_cast<const f32x4*>(vall + 4 * j);
    f32x4 vd = *reinterpret_cast<const f32x4*>(vall + 128 + 4 * j);
    float ps = xv.x * vs.x + xv.y * vs.y + xv.z * vs.z + xv.w * vs.w;
    float pd = xv.x * vd.x + xv.y * vd.y + xv.z * vd.z + xv.w * vd.w;
#pragma unroll
    for (int off = 1; off <= 16; off <<= 1) {
        ps += __shfl_xor(ps, off, 64);
        pd += __shfl_xor(pd, off, 64);
    }
    if (j == 0 && n < N) { s_src[n] = ps; s_dst[n] = pd; }
}

// hierarchical exclusive scan of cnt[N] -> start[N+1], cursor[N]  (proven 3-kernel)
__global__ void k_scan1(const int* __restrict__ cnt, int* __restrict__ bsum, int N) {
    __shared__ int red[256];
    int t = threadIdx.x;
    int idx = blockIdx.x * 256 + t;
    red[t] = (idx < N) ? cnt[idx] : 0;
    __syncthreads();
    for (int off = 128; off > 0; off >>= 1) {
        if (t < off) red[t] += red[t + off];
        __syncthreads();
    }
    if (t == 0) bsum[blockIdx.x] = red[0];
}

__global__ void k_scan2(int* __restrict__ bsum, int nb) {
    __shared__ int tmp[256];
    int t = threadIdx.x;
    int v = (t < nb) ? bsum[t] : 0;
    tmp[t] = v;
    __syncthreads();
    for (int off = 1; off < 256; off <<= 1) {
        int add = (t >= off) ? tmp[t - off] : 0;
        __syncthreads();
        tmp[t] += add;
        __syncthreads();
    }
    if (t < nb) bsum[t] = tmp[t] - v;  // exclusive
}

__global__ void k_scan3(const int* __restrict__ cnt, const int* __restrict__ bsum,
                        int* __restrict__ start, int* __restrict__ cursor, int N, int E) {
    __shared__ int tmp[256];
    int t = threadIdx.x;
    int idx = blockIdx.x * 256 + t;
    int v = (idx < N) ? cnt[idx] : 0;
    tmp[t] = v;
    __syncthreads();
    for (int off = 1; off < 256; off <<= 1) {
        int add = (t >= off) ? tmp[t - off] : 0;
        __syncthreads();
        tmp[t] += add;
        __syncthreads();
    }
    if (idx < N) {
        int excl = tmp[t] - v + bsum[blockIdx.x];
        start[idx] = excl;
        cursor[idx] = excl;
    }
    if (blockIdx.x == 0 && t == 0) start[N] = E;
}

// Bucketing WITH payload relocation + full score/exp fusion: one 16-lane group
// per edge. Linear reads (edges, emb rows f32x4/lane); L3-resident reads
// (s_src[src], s_dst[dst]); random writes: 128 B embS row (one full line) +
// ONE packed int2 (dst, float_bits(e)) -> one 64 B sector per edge (was two).
__global__ void k_scatter_copy(const int* __restrict__ e1, int E1,
                               const int* __restrict__ e2, int E2,
                               int* __restrict__ cursor,
                               const float* __restrict__ emb1, const float* __restrict__ emb2,
                               const float* __restrict__ vall,
                               const float* __restrict__ s_src, const float* __restrict__ s_dst,
                               int2* __restrict__ sdt,
                               __hip_bfloat16* __restrict__ embS) {
    int wid = (int)((blockIdx.x * (size_t)blockDim.x + threadIdx.x) >> 6);
    int lane = threadIdx.x & 63;
    int g = lane >> 4, t = lane & 15;
    int e = wid * 4 + g;
    int E = E1 + E2;
    if (e >= E) return;
    int src, dst;
    const float* ep;
    if (e < E1) { src = e1[e]; dst = e1[E1 + e]; ep = emb1 + (size_t)e * 64; }
    else { int q = e - E1; src = e2[q]; dst = e2[E2 + q]; ep = emb2 + (size_t)q * 64; }
    f32x4 em = *reinterpret_cast<const f32x4*>(ep + 4 * t);
    f32x4 r4 = *reinterpret_cast<const f32x4*>(vall + 256 + 4 * t);
    float tv = em.x * r4.x + em.y * r4.y + em.z * r4.z + em.w * r4.w;
#pragma unroll
    for (int off = 1; off <= 8; off <<= 1) tv += __shfl_xor(tv, off, 64);
    // score -> exp, identical op sequence to the previous gather (bit-identical)
    float sc = s_src[src] + s_dst[dst] + tv;
    float pz = sc > 0.f ? sc : LRELU_ALPHA * sc;
    float ee = __expf(-pz);
    int p = 0;
    if (t == 0) p = atomicAdd(&cursor[src], 1);
    p = __shfl(p, g * 16, 64);  // broadcast from group leader
    bf16x4 eb;
#pragma unroll
    for (int k = 0; k < 4; ++k) eb[k] = (__bf16)em[k];
    *reinterpret_cast<bf16x4*>(embS + (size_t)p * 64 + 4 * t) = eb;
    if (t == 0) sdt[p] = make_int2(dst, __float_as_int(ee));
}

// one wave per node, group-parallel (4 groups x 16 lanes, 8 edges/iter).
// Pure weighted accumulation: e_e precomputed in scatter; streams (sdt, embS)
// are linear within the node's segment; XBf reads random but L3-resident.
__global__ void k_gather(const __hip_bfloat16* __restrict__ XBf,
                         const __hip_bfloat16* __restrict__ embS,
                         const int2* __restrict__ sdt,
                         const int* __restrict__ start,
                         __hip_bfloat16* __restrict__ G, float* __restrict__ sxf, int N) {
    int n = (int)((blockIdx.x * (size_t)blockDim.x + threadIdx.x) >> 6);
    int lane = threadIdx.x & 63;
    if (n >= N) return;
    n = __builtin_amdgcn_readfirstlane(n);
    int g = lane >> 4;   // edge slot within a 4-edge batch
    int t = lane & 15;   // lane within group
    int b = start[n], en = start[n + 1];
    f32x4 w4 = {0.f, 0.f, 0.f, 0.f};
    float u8[8] = {0.f, 0.f, 0.f, 0.f, 0.f, 0.f, 0.f, 0.f};
    float rs = 0.f;

    for (int p = b; p < en; p += 8) {
        int q0 = p + g;
        int q1 = p + 4 + g;
        int c0 = (q0 < en) ? q0 : en - 1;   // en > b here, so en-1 valid
        int c1 = (q1 < en) ? q1 : en - 1;
        int2 s0 = sdt[c0], s1 = sdt[c1];
        int d0 = s0.x, d1 = s1.x;
        float e0 = __int_as_float(s0.y);
        float e1v = __int_as_float(s1.y);
        bf16x4 ev0 = *reinterpret_cast<const bf16x4*>(embS + (size_t)c0 * 64 + 4 * t);
        bf16x4 ev1 = *reinterpret_cast<const bf16x4*>(embS + (size_t)c1 * 64 + 4 * t);
        bf16x8 xv0 = *reinterpret_cast<const bf16x8*>(XBf + (size_t)d0 * 128 + 8 * t);
        bf16x8 xv1 = *reinterpret_cast<const bf16x8*>(XBf + (size_t)d1 * 128 + 8 * t);
        if (q0 >= en) e0 = 0.f;
        if (q1 >= en) e1v = 0.f;
        rs += e0 + e1v;
        f32x4 f0 = {(float)ev0[0], (float)ev0[1], (float)ev0[2], (float)ev0[3]};
        f32x4 f1 = {(float)ev1[0], (float)ev1[1], (float)ev1[2], (float)ev1[3]};
        w4 += e0 * f0 + e1v * f1;
#pragma unroll
        for (int j = 0; j < 8; ++j)
            u8[j] += e0 * (float)xv0[j] + e1v * (float)xv1[j];
    }

    // combine the 4 per-group partials (once per node)
#pragma unroll
    for (int j = 0; j < 8; ++j) {
        u8[j] += __shfl_xor(u8[j], 16, 64);
        u8[j] += __shfl_xor(u8[j], 32, 64);
    }
#pragma unroll
    for (int j = 0; j < 4; ++j) {
        w4[j] += __shfl_xor(w4[j], 16, 64);
        w4[j] += __shfl_xor(w4[j], 32, 64);
    }
    rs += __shfl_xor(rs, 16, 64);
    rs += __shfl_xor(rs, 32, 64);

    float inv = (rs == 0.f) ? 0.f : 1.f / rs;
    if (lane < 16) {
        __hip_bfloat16* gp = G + (size_t)n * 192;
        bf16x8 uu;
#pragma unroll
        for (int j = 0; j < 8; ++j) uu[j] = (__bf16)(u8[j] * inv);
        *reinterpret_cast<bf16x8*>(gp + 8 * lane) = uu;
        bf16x4 ww;
#pragma unroll
        for (int j = 0; j < 4; ++j) ww[j] = (__bf16)(w4[j] * inv);
        *reinterpret_cast<bf16x4*>(gp + 128 + 4 * lane) = ww;
        if (lane == 0) sxf[n] = (rs == 0.f) ? 0.f : 1.f;
    }
}

// out[n][o] = elu( sxf[n] * (x[n].a_src[o] + G[n].[a_dst|a_rel][o]) ) via bf16 MFMA.
__global__ __launch_bounds__(256) void k_mfma(
    const __hip_bfloat16* __restrict__ XBf, const __hip_bfloat16* __restrict__ G,
    const __hip_bfloat16* __restrict__ ABf, const float* __restrict__ sxf,
    float* __restrict__ out, int N) {
    int lane = threadIdx.x & 63;
    int wave = threadIdx.x >> 6;
    int m0 = blockIdx.x * 64 + wave * 16;
    int q = lane >> 4, m = lane & 15;
    int rowm = m0 + m; if (rowm >= N) rowm = N - 1;  // clamp; garbage rows never stored
    const __hip_bfloat16* xr = XBf + (size_t)rowm * 128 + q * 8;
    const __hip_bfloat16* gr = G + (size_t)rowm * 192 + q * 8;
    const __hip_bfloat16* br = ABf + (size_t)m * 320 + q * 8;
    f32x4 acc[8];
#pragma unroll
    for (int c = 0; c < 8; ++c) acc[c] = f32x4{0.f, 0.f, 0.f, 0.f};

#pragma unroll
    for (int s = 0; s < 4; ++s) {  // k = s*32 .. +32 from XBf
        bf16x8 af = *reinterpret_cast<const bf16x8*>(xr + s * 32);
#pragma unroll
        for (int c = 0; c < 8; ++c) {
            bf16x8 bf = *reinterpret_cast<const bf16x8*>(br + (size_t)c * 16 * 320 + s * 32);
            acc[c] = __builtin_amdgcn_mfma_f32_16x16x32_bf16(af, bf, acc[c], 0, 0, 0);
        }
    }
#pragma unroll
    for (int s = 0; s < 6; ++s) {  // k = 128 + s*32 .. +32 from G
        bf16x8 af = *reinterpret_cast<const bf16x8*>(gr + s * 32);
#pragma unroll
        for (int c = 0; c < 8; ++c) {
            bf16x8 bf = *reinterpret_cast<const bf16x8*>(br + (size_t)c * 16 * 320 + 128 + s * 32);
            acc[c] = __builtin_amdgcn_mfma_f32_16x16x32_bf16(af, bf, acc[c], 0, 0, 0);
        }
    }

    float sxr[4];
#pragma unroll
    for (int r = 0; r < 4; ++r) {
        int n = m0 + q * 4 + r;
        sxr[r] = (n < N) ? sxf[n] : 0.f;
    }
#pragma unroll
    for (int c = 0; c < 8; ++c) {
#pragma unroll
        for (int r = 0; r < 4; ++r) {
            int n = m0 + q * 4 + r;
            if (n < N) {
                float h = acc[c][r] * sxr[r];
                out[(size_t)n * 128 + c * 16 + m] = h > 0.f ? h : __expf(h) - 1.f;
            }
        }
    }
}

extern "C" void kernel_launch(void* const* d_in, const int* in_sizes, int n_in,
                              void* d_out, int out_size, void* d_ws, size_t ws_size,
                              hipStream_t stream) {
    const float* x    = (const float*)d_in[0];
    const int*   e1   = (const int*)d_in[1];
    const float* emb1 = (const float*)d_in[2];
    const int*   e2   = (const int*)d_in[3];
    const float* emb2 = (const float*)d_in[4];
    const float* a    = (const float*)d_in[5];
    const float* a2   = (const float*)d_in[6];
    float* out = (float*)d_out;

    const int N  = in_sizes[0] / 128;
    const int E1 = in_sizes[1] / 2;
    const int E2 = in_sizes[3] / 2;
    const int E  = E1 + E2;
    const int NB = (N + 255) / 256;  // <=256 (N<=65536)

    // workspace layout
    float* ws    = (float*)d_ws;
    float* vall  = ws;                                   // 512 f
    __hip_bfloat16* ABf = (__hip_bfloat16*)(ws + 512);   // 128*320 bf16 = 20480 f
    float* s_src = ws + 512 + 20480;                     // N
    float* s_dst = s_src + N;                            // N
    float* sxf   = s_dst + N;                            // N
    int*   cnt    = (int*)(sxf + N);                     // N
    int*   bsum   = cnt + N;                             // 256
    int*   start  = bsum + 256;                          // N+1
    int*   cursor = start + N + 1;                       // N+1
    size_t so = (size_t)((char*)(cursor + N + 1) - (char*)d_ws);
    so = (so + 15) & ~(size_t)15;
    int2*  sdt = (int2*)((char*)d_ws + so);              // E int2 (dst, bits(e))
    size_t eo = so + (size_t)E * sizeof(int2);
    eo = (eo + 127) & ~(size_t)127;
    __hip_bfloat16* embS = (__hip_bfloat16*)((char*)d_ws + eo);  // E*64 bf16 = 128 B/row
    size_t xo = eo + (size_t)E * 64 * sizeof(__hip_bfloat16);
    xo = (xo + 15) & ~(size_t)15;
    __hip_bfloat16* XBf = (__hip_bfloat16*)((char*)d_ws + xo);  // N*128 bf16
    size_t go = xo + (size_t)N * 128 * sizeof(__hip_bfloat16);
    go = (go + 15) & ~(size_t)15;
    __hip_bfloat16* G = (__hip_bfloat16*)((char*)d_ws + go);    // N*192 bf16

    size_t needed = go + (size_t)N * 192 * sizeof(__hip_bfloat16);
    if (ws_size < needed) return;  // defensive

    hipMemsetAsync(cnt, 0, (size_t)N * sizeof(int), stream);

    int gridPC = ((E > 128 * 320 ? E : 128 * 320) + 255) / 256;
    k_prep_count<<<gridPC, 256, 0, stream>>>(a, a2, vall, ABf, e1, E1, e2, E2, cnt);
    int W = (N + 1) / 2;  // waves for node_scores (2 nodes/wave)
    k_node_scores<<<(W * 64 + 255) / 256, 256, 0, stream>>>(x, vall, s_src, s_dst, XBf, N);
    k_scan1<<<NB, 256, 0, stream>>>(cnt, bsum, N);
    k_scan2<<<1, 256, 0, stream>>>(bsum, NB);
    k_scan3<<<NB, 256, 0, stream>>>(cnt, bsum, start, cursor, N, E);
    int Wsc = (E + 3) / 4;  // waves for scatter_copy (4 edges/wave)
    k_scatter_copy<<<(Wsc * 64 + 255) / 256, 256, 0, stream>>>(
        e1, E1, e2, E2, cursor, emb1, emb2, vall, s_src, s_dst, sdt, embS);
    k_gather<<<(N * 64 + 255) / 256, 256, 0, stream>>>(
        XBf, embS, sdt, start, G, sxf, N);
    k_mfma<<<(N + 63) / 64, 256, 0, stream>>>(XBf, G, ABf, sxf, out, N);
}